// Round 7
// baseline (7364.304 us; speedup 1.0000x reference)
//
#include <hip/hip_runtime.h>
#include <math.h>

#define B_ 256
#define T_ 128
#define D_ 64
#define H_ 512
#define A_ 128
#define O_ 32

typedef __attribute__((ext_vector_type(8))) short short8;
typedef __attribute__((ext_vector_type(8))) unsigned short ushort8;
typedef __attribute__((ext_vector_type(4))) float floatx4;
typedef __attribute__((ext_vector_type(4))) unsigned int uintx4;
typedef unsigned long long ull;

__device__ __forceinline__ float sp_(float x) {
    return fmaxf(x, 0.f) + log1pf(expf(-fabsf(x)));
}
__device__ __forceinline__ float sigm_(float x) {
    return 1.f / (1.f + expf(-x));
}
__device__ __forceinline__ unsigned short f2bf_(float f) {
    unsigned int u = __float_as_uint(f);
    return (unsigned short)((u + 0x7FFFu + ((u >> 16) & 1u)) >> 16);
}
__device__ __forceinline__ float bf2f_(unsigned short u) {
    return __uint_as_float(((unsigned)u) << 16);
}

// ---- raw MALL-coherent (sc0 sc1) ops for CROSS-BLOCK traffic only ----------
// R13-R16: sc0-only has no cross-CU visibility on gfx950; no XCD scope exists.
// Cross-block exchange floor = MALL round trip. Block-local history (KhG/VhG)
// uses PLAIN cached ops instead (see R18 note in fused phase).
__device__ __forceinline__ void ld16sc(uintx4& d, const void* p) {
    asm volatile("global_load_dwordx4 %0, %1, off sc0 sc1"
                 : "=v"(d) : "v"(p) : "memory");
}
__device__ __forceinline__ void st64sc(ull* p, ull v) {
    asm volatile("global_store_dwordx2 %0, %1, off sc0 sc1"
                 :: "v"(p), "v"(v) : "memory");
}
__device__ __forceinline__ void vmwait4(uintx4& a, uintx4& b, uintx4& c,
                                        uintx4& d) {
    asm volatile("s_waitcnt vmcnt(0)"
                 : "+v"(a), "+v"(b), "+v"(c), "+v"(d)::"memory");
}
__device__ __forceinline__ void vmwait8(uintx4& a, uintx4& b, uintx4& c,
                                        uintx4& d, uintx4& e, uintx4& f,
                                        uintx4& g, uintx4& h) {
    asm volatile("s_waitcnt vmcnt(0)"
                 : "+v"(a), "+v"(b), "+v"(c), "+v"(d), "+v"(e), "+v"(f),
                   "+v"(g), "+v"(h)::"memory");
}
__device__ __forceinline__ floatx4 u2f_(uintx4 u) {
    union { uintx4 u; floatx4 f; } c;
    c.u = u;
    return c.f;
}
__device__ __forceinline__ void stf_(float* p, float v) {
    __hip_atomic_store(p, v, __ATOMIC_RELAXED, __HIP_MEMORY_SCOPE_SYSTEM);
}

// ---------------- init: hpack = 0, flags = 0 --------------------------------
__global__ void init_kernel(unsigned short* __restrict__ hpack,
                            unsigned* __restrict__ bar) {
    int i = blockIdx.x * 256 + threadIdx.x;
    if (i < B_ * H_) hpack[i] = 0;
    if (i < 8192) bar[i] = 0u;
}

// -------- pack all weights into MFMA B-frag bf16 order ----------------------
__global__ void pack_w_kernel(const float* __restrict__ W_gd,
                              const float* __restrict__ W_tau,
                              const float* __restrict__ Wk,
                              const float* __restrict__ Wv,
                              unsigned short* __restrict__ Wpack) {
    int gid = blockIdx.x * 256 + threadIdx.x;
    if (gid >= 1114112) return;
    int j = gid & 7;
    int l = (gid >> 3) & 63;
    int kpart = (l >> 4) * 8 + j;
    int npart = l & 15;
    float v;
    if (gid < 786432) {
        int f = gid >> 9;
        int s = f % 3;
        int rem = f / 3;
        int kb = rem & 15, ct = rem >> 4;
        int k = kb * 32 + kpart;
        int c = ct * 16 + npart;
        if (s == 0)      v = W_gd[(size_t)(D_ + k) * 1024 + c];
        else if (s == 1) v = W_gd[(size_t)(D_ + k) * 1024 + 512 + c];
        else             v = W_tau[(size_t)k * 512 + c];
    } else if (gid < 851968) {
        int r = gid - 786432;
        int f = r >> 9;
        int s = f & 1, kb = (f >> 1) & 1, ct = f >> 2;
        int k = kb * 32 + kpart;
        int c = ct * 16 + npart;
        v = W_gd[(size_t)k * 1024 + s * 512 + c];
    } else if (gid < 983040) {
        int r = gid - 851968;
        int f = r >> 9;
        int s = f & 1, kb = (f >> 1) & 3, ct = f >> 3;
        int k = kb * 32 + kpart;
        int c = ct * 16 + npart;
        v = W_gd[(size_t)(D_ + H_ + k) * 1024 + s * 512 + c];
    } else {
        int r = gid - 983040;
        int f = r >> 9;
        int kb = f & 15, c4 = f >> 4;
        int k = kb * 32 + kpart;
        int n = (c4 & 7) * 16 + npart;
        v = (c4 < 8) ? Wk[(size_t)k * A_ + n] : Wv[(size_t)k * A_ + n];
    }
    Wpack[gid] = f2bf_(v);
}

// ---- group barrier: 8 blocks, per-block flag slots ----
__device__ __forceinline__ void gsyncF(unsigned* flags, int j, unsigned cnt) {
    asm volatile("s_waitcnt vmcnt(0)" ::: "memory");  // drain all data stores
    __syncthreads();
    if (threadIdx.x == 0)
        __hip_atomic_store(flags + j * 64, cnt, __ATOMIC_RELAXED,
                           __HIP_MEMORY_SCOPE_SYSTEM);
    if (threadIdx.x < 8) {
        while (__hip_atomic_load(flags + threadIdx.x * 64, __ATOMIC_RELAXED,
                                 __HIP_MEMORY_SCOPE_SYSTEM) < cnt) {
            __builtin_amdgcn_s_sleep(1);
        }
    }
    __syncthreads();
}

struct P {
    const float *x, *dts, *Wq, *bq, *bk, *bv, *b_gd, *b_tau, *gleak, *cm,
        *W_fc, *b_fc;
    float *h, *out;
    unsigned short *KhG, *VhG;  // [B][T][A] bf16 shared history, PLAIN cached
    const unsigned short *Wy, *Wx, *Wc, *Wkv;
    unsigned short *hpack, *yapack, *ybpack;  // [m_tile][strip][row][col]
    unsigned* bar;
};

__global__ __launch_bounds__(256, 1) void fused_kernel(P p) {
    const int tid = threadIdx.x;
    const int bid = blockIdx.x;
    const int lane = tid & 63;
    const int wave = tid >> 6;            // 0..3
    const int g = bid & 15;               // group of 8 blocks
    const int j = bid >> 4;               // block within group 0..7
    const int ct = j * 4 + wave;          // channel strip 0..31
    unsigned* flags = p.bar + g * 512;
    unsigned cnt = 0;

    __shared__ float WqL[D_ * 129];                          // 33 KB
    __shared__ __align__(16) float xsL[16][64];              // 4 KB  x(t) rows
    __shared__ float qL[16][A_];                             // 8 KB
    __shared__ float scL[16][T_];                            // 8 KB  scores/e
    __shared__ __align__(16) float ctxL[16][132];            // 8.3 KB
    __shared__ __align__(16) unsigned short AsL[32 * 256];   // 16 KB staged A
    __shared__ __align__(16) unsigned short ypbuf[4 * 256];  // 2 KB transpose

    const int quad = lane >> 4;
    const int c = ct * 16 + (lane & 15);
    const float btau = p.b_tau[c];
    const float lk = sp_(p.cm[c]) + sp_(p.gleak[c]) + 1e-6f;
    const float bgd_g = p.b_gd[c];
    const float bgd_d = p.b_gd[512 + c];
    const int aoff = (quad >> 1) * 256 + (lane & 15) * 16 + (quad & 1) * 8;
    const int ypw = wave * 256 + (lane & 15);

    const int sub = tid >> 7;             // 0..1 (final fc only)
    const int tl = tid & 127;
    const int rfc = g * 16 + j * 2 + sub; // this block's 2 fc rows

    // ---- persistent register weights: 60 frags (240 VGPRs) ----
    short8 wg[16], wd[16], wt[16];
    short8 wxg[2], wxd[2], wcg[4], wcd[4];
    {
        const short8* Wy8 = (const short8*)p.Wy;
        #pragma unroll
        for (int kb = 0; kb < 16; ++kb) {
            wg[kb] = Wy8[((ct * 16 + kb) * 3 + 0) * 64 + lane];
            wd[kb] = Wy8[((ct * 16 + kb) * 3 + 1) * 64 + lane];
            wt[kb] = Wy8[((ct * 16 + kb) * 3 + 2) * 64 + lane];
        }
        const short8* Wx8 = (const short8*)p.Wx;
        const short8* Wc8 = (const short8*)p.Wc;
        #pragma unroll
        for (int kb = 0; kb < 2; ++kb) {
            wxg[kb] = Wx8[((ct * 2 + kb) * 2 + 0) * 64 + lane];
            wxd[kb] = Wx8[((ct * 2 + kb) * 2 + 1) * 64 + lane];
        }
        #pragma unroll
        for (int kb = 0; kb < 4; ++kb) {
            wcg[kb] = Wc8[((ct * 4 + kb) * 2 + 0) * 64 + lane];
            wcd[kb] = Wc8[((ct * 4 + kb) * 2 + 1) * 64 + lane];
        }
    }

    for (int i = tid; i < D_ * A_; i += 256) {
        int d = i >> 7, a = i & 127;
        WqL[d * 129 + a] = p.Wq[i];
    }

    floatx4 hreg = {0.f, 0.f, 0.f, 0.f};
    floatx4 rk1, rk2, rk3, baseg, based, ycur, dt4;

    const short8* Wkv8 = (const short8*)p.Wkv;
    const int row = tid >> 4;   // 0..15 (fused-phase attention row)
    const int k0 = tid & 15;    // 0..15
    const size_t grow = (size_t)(g * 16 + row);

    __syncthreads();  // WqL ready

    for (int t = 0; t < T_; ++t) {
        // ========== fused phase: KV + attention (16 rows, redundant) + stage1
        float4 xr[4];
        {
            // AsL <- hpack (guarded by stage4(t-1) barrier / init)
            uintx4 av[4];
            const unsigned short* src = p.hpack + g * 8192;
            #pragma unroll
            for (int i = 0; i < 4; ++i)
                ld16sc(av[i], src + (size_t)tid * 8 + i * 2048);
            // x(t) rows -> LDS (plain cached; read-only input)
            if (tid < 64)
                ((float4*)&xsL[tid >> 2][0])[tid & 3] =
                    ((const float4*)&p.x[((g * 16 + (tid >> 2)) * T_ + t) *
                                         D_])[tid & 3];
            #pragma unroll
            for (int i = 0; i < 4; ++i)
                dt4[i] = p.dts[(g * 16 + quad * 4 + i) * T_ + t];
            {
                const float4* xrow =
                    (const float4*)&p.x[((g * 16 + (lane & 15)) * T_ + t) * D_];
                #pragma unroll
                for (int kb = 0; kb < 2; ++kb) {
                    xr[2 * kb] = xrow[kb * 8 + quad * 2];
                    xr[2 * kb + 1] = xrow[kb * 8 + quad * 2 + 1];
                }
            }
            vmwait4(av[0], av[1], av[2], av[3]);
            #pragma unroll
            for (int i = 0; i < 4; ++i)
                ((uintx4*)AsL)[tid + i * 256] = av[i];
        }
        __syncthreads();  // AsL + xsL ready

        // K/V[key t-1] = h(t) @ Wk/Wv + bias, FULL (all 16 rows x 128 a).
        // Redundant on all 8 blocks -> bit-identical -> each block only ever
        // READS KhG/VhG lines it wrote itself => plain cached path is safe
        // with no cross-block visibility requirement (replaces the partial-sum
        // exchange + merge of R0-R17's Kpart/Vpart).
        if (t > 0) {
            #pragma unroll
            for (int h4 = 0; h4 < 4; ++h4) {
                const int c4 = wave + h4 * 4;  // 0..7=K cols, 8..15=V cols
                floatx4 acc = {0.f, 0.f, 0.f, 0.f};
                #pragma unroll
                for (int kb = 0; kb < 16; ++kb) {
                    short8 a = *(const short8*)(AsL + kb * 512 + aoff);
                    acc = __builtin_amdgcn_mfma_f32_16x16x32_bf16(
                        a, Wkv8[(c4 * 16 + kb) * 64 + lane], acc, 0, 0, 0);
                }
                const int ac = (c4 & 7) * 16 + (lane & 15);
                unsigned short* dst = (c4 < 8) ? p.KhG : p.VhG;
                const float bias = ((c4 < 8) ? p.bk : p.bv)[ac];
                #pragma unroll
                for (int i = 0; i < 4; ++i) {
                    size_t rr = (size_t)(g * 16 + quad * 4 + i);
                    dst[(rr * T_ + (t - 1)) * A_ + ac] = f2bf_(acc[i] + bias);
                }
            }
        }
        // q(t) for all 16 rows, fp32 path (same numerics as before)
        {
            float qa[8];
            #pragma unroll
            for (int n = 0; n < 8; ++n) qa[n] = p.bq[k0 * 8 + n];
            for (int d = 0; d < D_; ++d) {
                float xv = xsL[row][d];
                #pragma unroll
                for (int n = 0; n < 8; ++n)
                    qa[n] += xv * WqL[d * 129 + k0 * 8 + n];
            }
            #pragma unroll
            for (int n = 0; n < 8; ++n) qL[row][k0 * 8 + n] = qa[n];
        }
        asm volatile("s_waitcnt vmcnt(0)" ::: "memory");  // KV stores -> L1
        __syncthreads();  // qL ready; new K/V readable (same-CU L1)

        if (t > 0) {
            const float rscale = 0.08838834764831845f;  // 1/sqrt(128)
            // scores: thread (row,k0) handles keys s = k0, k0+16, ...
            for (int s = k0; s < t; s += 16) {
                const ushort8* K8 =
                    (const ushort8*)&p.KhG[(grow * T_ + s) * A_];
                float a2 = 0.f;
                #pragma unroll
                for (int w8 = 0; w8 < 16; ++w8) {
                    ushort8 k8 = K8[w8];
                    #pragma unroll
                    for (int i = 0; i < 8; ++i)
                        a2 += bf2f_(k8[i]) * qL[row][w8 * 8 + i];
                }
                scL[row][s] = a2 * rscale;
            }
            // softmax per row across its 16 threads (lanes contiguous)
            float m = -1e30f;
            for (int s = k0; s < t; s += 16) m = fmaxf(m, scL[row][s]);
            #pragma unroll
            for (int off = 8; off > 0; off >>= 1)
                m = fmaxf(m, __shfl_xor(m, off, 16));
            float ssum = 0.f;
            for (int s = k0; s < t; s += 16) {
                float e = expf(scL[row][s] - m);
                scL[row][s] = e;
                ssum += e;
            }
            #pragma unroll
            for (int off = 8; off > 0; off >>= 1)
                ssum += __shfl_xor(ssum, off, 16);
            float rs = 1.f / ssum;
            __syncthreads();  // all e-values of the row visible
            // PV: thread (row,k0) accumulates ctx[row][k0*8 .. +7]
            float ca[8] = {0.f, 0.f, 0.f, 0.f, 0.f, 0.f, 0.f, 0.f};
            for (int s = 0; s < t; ++s) {
                float w = scL[row][s];
                ushort8 v8 = *(const ushort8*)&p.VhG[(grow * T_ + s) * A_ +
                                                     k0 * 8];
                #pragma unroll
                for (int i = 0; i < 8; ++i) ca[i] += w * bf2f_(v8[i]);
            }
            #pragma unroll
            for (int i = 0; i < 8; ++i) ctxL[row][k0 * 8 + i] = ca[i] * rs;
        } else {
            #pragma unroll
            for (int i = 0; i < 8; ++i) ctxL[row][k0 * 8 + i] = 0.f;
        }
        __syncthreads();  // ctxL ready

        // ---- stage 1 (ctx from LDS; no ctx exchange barrier needed) ----
        {
            floatx4 bg = {0.f, 0.f, 0.f, 0.f};
            floatx4 bd = {0.f, 0.f, 0.f, 0.f};
            #pragma unroll
            for (int kb = 0; kb < 2; ++kb) {
                float4 u = xr[2 * kb], v = xr[2 * kb + 1];
                short8 ax;
                ax[0] = (short)f2bf_(u.x); ax[1] = (short)f2bf_(u.y);
                ax[2] = (short)f2bf_(u.z); ax[3] = (short)f2bf_(u.w);
                ax[4] = (short)f2bf_(v.x); ax[5] = (short)f2bf_(v.y);
                ax[6] = (short)f2bf_(v.z); ax[7] = (short)f2bf_(v.w);
                bg = __builtin_amdgcn_mfma_f32_16x16x32_bf16(ax, wxg[kb], bg, 0, 0, 0);
                bd = __builtin_amdgcn_mfma_f32_16x16x32_bf16(ax, wxd[kb], bd, 0, 0, 0);
            }
            const int mrow = lane & 15;
            #pragma unroll
            for (int kb = 0; kb < 4; ++kb) {
                float4 f0 = *(const float4*)&ctxL[mrow][kb * 32 + quad * 8];
                float4 f1 = *(const float4*)&ctxL[mrow][kb * 32 + quad * 8 + 4];
                short8 ac;
                ac[0] = (short)f2bf_(f0.x); ac[1] = (short)f2bf_(f0.y);
                ac[2] = (short)f2bf_(f0.z); ac[3] = (short)f2bf_(f0.w);
                ac[4] = (short)f2bf_(f1.x); ac[5] = (short)f2bf_(f1.y);
                ac[6] = (short)f2bf_(f1.z); ac[7] = (short)f2bf_(f1.w);
                bg = __builtin_amdgcn_mfma_f32_16x16x32_bf16(ac, wcg[kb], bg, 0, 0, 0);
                bd = __builtin_amdgcn_mfma_f32_16x16x32_bf16(ac, wcd[kb], bd, 0, 0, 0);
            }
            floatx4 ag = {0.f, 0.f, 0.f, 0.f};
            floatx4 ad = {0.f, 0.f, 0.f, 0.f};
            floatx4 at = {0.f, 0.f, 0.f, 0.f};
            #pragma unroll
            for (int kb = 0; kb < 16; ++kb) {
                short8 a = *(const short8*)(AsL + kb * 512 + aoff);
                ag = __builtin_amdgcn_mfma_f32_16x16x32_bf16(a, wg[kb], ag, 0, 0, 0);
                ad = __builtin_amdgcn_mfma_f32_16x16x32_bf16(a, wd[kb], ad, 0, 0, 0);
                at = __builtin_amdgcn_mfma_f32_16x16x32_bf16(a, wt[kb], at, 0, 0, 0);
            }
            #pragma unroll
            for (int i = 0; i < 4; ++i) {
                baseg[i] = bg[i] + bgd_g;
                based[i] = bd[i] + bgd_d;
                float gate = ag[i] + baseg[i];
                float dyn = ad[i] + based[i];
                float tau = sp_(at[i] + btau);
                float ki = (sigm_(gate) * tanhf(dyn) - hreg[i]) / (tau + lk);
                rk1[i] = ki;
                float yn = hreg[i] + dt4[i] * ki * (1.f / 3.f);
                ycur[i] = yn;
                ypbuf[ypw + (quad * 4 + i) * 16] = f2bf_(yn);
            }
            __syncthreads();
            st64sc((ull*)p.yapack + g * 2048 + j * 256 + tid,
                   ((const ull*)ypbuf)[tid]);
        }
        gsyncF(flags, j, ++cnt);  // BARRIER 1 (of 4)

        // ---------- stages 2..4 ----------
        #pragma unroll 1
        for (int stage = 2; stage <= 4; ++stage) {
            const unsigned short* ysrc =
                (stage == 2) ? p.yapack : (stage == 3) ? p.ybpack : p.yapack;
            unsigned short* ydst =
                (stage == 2) ? p.ybpack : (stage == 3) ? p.yapack : p.hpack;
            {
                const unsigned short* src = ysrc + g * 8192;
                uintx4 av[4];
                #pragma unroll
                for (int i = 0; i < 4; ++i)
                    ld16sc(av[i], src + (size_t)tid * 8 + i * 2048);
                vmwait4(av[0], av[1], av[2], av[3]);
                #pragma unroll
                for (int i = 0; i < 4; ++i)
                    ((uintx4*)AsL)[tid + i * 256] = av[i];
            }
            __syncthreads();
            floatx4 ag = {0.f, 0.f, 0.f, 0.f};
            floatx4 ad = {0.f, 0.f, 0.f, 0.f};
            floatx4 at = {0.f, 0.f, 0.f, 0.f};
            #pragma unroll
            for (int kb = 0; kb < 16; ++kb) {
                short8 a = *(const short8*)(AsL + kb * 512 + aoff);
                ag = __builtin_amdgcn_mfma_f32_16x16x32_bf16(a, wg[kb], ag, 0, 0, 0);
                ad = __builtin_amdgcn_mfma_f32_16x16x32_bf16(a, wd[kb], ad, 0, 0, 0);
                at = __builtin_amdgcn_mfma_f32_16x16x32_bf16(a, wt[kb], at, 0, 0, 0);
            }
            #pragma unroll
            for (int i = 0; i < 4; ++i) {
                float gate = ag[i] + baseg[i];
                float dyn = ad[i] + based[i];
                float tau = sp_(at[i] + btau);
                float ki = (sigm_(gate) * tanhf(dyn) - ycur[i]) / (tau + lk);
                float yn;
                if (stage == 2) {
                    rk2[i] = ki;
                    yn = hreg[i] + dt4[i] * (ki - rk1[i] * (1.f / 3.f));
                } else if (stage == 3) {
                    rk3[i] = ki;
                    yn = hreg[i] + dt4[i] * (rk1[i] - rk2[i] + ki);
                } else {
                    yn = hreg[i] +
                         dt4[i] * (rk1[i] + 3.f * rk2[i] + 3.f * rk3[i] + ki) * 0.125f;
                    hreg[i] = yn;
                }
                ycur[i] = yn;
                ypbuf[ypw + (quad * 4 + i) * 16] = f2bf_(yn);
            }
            __syncthreads();
            st64sc((ull*)ydst + g * 2048 + j * 256 + tid,
                   ((const ull*)ypbuf)[tid]);
            gsyncF(flags, j, ++cnt);  // BARRIERS 2..4
        }
    }

    // ---------- write final h, then fc ----------
    #pragma unroll
    for (int i = 0; i < 4; ++i)
        stf_(p.h + (g * 16 + quad * 4 + i) * H_ + c, hreg[i]);
    gsyncF(flags, j, ++cnt);
    {
        float* fcred = (float*)scL;  // reuse LDS
        const int o = tl & 31, ks = tl >> 5;  // ks 0..3
        float acc = 0.f;
        const float* hrow = p.h + rfc * H_ + ks * 128;
        const float* wcol = p.W_fc + ks * 128 * O_ + o;
        #pragma unroll 1
        for (int rd = 0; rd < 4; ++rd) {
            uintx4 hh[8];
            #pragma unroll
            for (int i = 0; i < 8; ++i)
                ld16sc(hh[i], hrow + rd * 32 + i * 4);
            vmwait8(hh[0], hh[1], hh[2], hh[3], hh[4], hh[5], hh[6], hh[7]);
            #pragma unroll
            for (int i = 0; i < 8; ++i) {
                floatx4 f = u2f_(hh[i]);
                #pragma unroll
                for (int e = 0; e < 4; ++e)
                    acc += f[e] * wcol[(rd * 32 + i * 4 + e) * O_];
            }
        }
        fcred[tid] = acc;
        __syncthreads();
        if (ks == 0)
            p.out[rfc * O_ + o] = acc + fcred[sub * 128 + o + 32] +
                                  fcred[sub * 128 + o + 64] +
                                  fcred[sub * 128 + o + 96] + p.b_fc[o];
    }
}

extern "C" void kernel_launch(void* const* d_in, const int* in_sizes, int n_in,
                              void* d_out, int out_size, void* d_ws,
                              size_t ws_size, hipStream_t stream) {
    (void)in_sizes; (void)n_in; (void)out_size; (void)ws_size;
    P p;
    p.x = (const float*)d_in[0];
    p.dts = (const float*)d_in[1];
    p.Wq = (const float*)d_in[2];
    p.bq = (const float*)d_in[3];
    const float* Wk = (const float*)d_in[4];
    p.bk = (const float*)d_in[5];
    const float* Wv = (const float*)d_in[6];
    p.bv = (const float*)d_in[7];
    const float* W_gd = (const float*)d_in[8];
    p.b_gd = (const float*)d_in[9];
    const float* W_tau = (const float*)d_in[10];
    p.b_tau = (const float*)d_in[11];
    p.gleak = (const float*)d_in[12];
    p.cm = (const float*)d_in[13];
    p.W_fc = (const float*)d_in[14];
    p.b_fc = (const float*)d_in[15];
    p.out = (float*)d_out;

    float* ws = (float*)d_ws;
    p.h = ws;                                  // B*H fp32 (512 KB)
    unsigned short* Wpack = (unsigned short*)(p.h + B_ * H_);
    p.Wy = Wpack;                              // 786432 ushorts
    p.Wx = Wpack + 786432;                     // 65536
    p.Wc = Wpack + 851968;                     // 131072
    p.Wkv = Wpack + 983040;                    // 131072
    p.hpack = Wpack + 1114112;                 // B*H ushorts
    p.yapack = p.hpack + B_ * H_;
    p.ybpack = p.yapack + B_ * H_;
    p.KhG = p.ybpack + B_ * H_;                // B*T*A bf16 (plain cached)
    p.VhG = p.KhG + (size_t)B_ * T_ * A_;      // B*T*A bf16
    p.bar = (unsigned*)(p.VhG + (size_t)B_ * T_ * A_);  // 8192 uints

    init_kernel<<<512, 256, 0, stream>>>(p.hpack, p.bar);
    pack_w_kernel<<<4352, 256, 0, stream>>>(W_gd, W_tau, Wk, Wv, Wpack);

    // 128 blocks x 256 threads, launch_bounds(256,1).
    // R17 post-mortem: intra-phase latency cuts were neutral -> per-phase time
    // is the barrier-exchange itself (L ~ 5us), compute ~0.5us. R18 removes
    // one of the 5 barriers per timestep: attention + stage1 are FUSED by
    // computing all 16 rows' attention redundantly per block. Enablers:
    // (1) full K/V[t-1] = h(t)@Wkv GEMM from the already-staged AsL (replaces
    //     the strip-partial Kpart/Vpart exchange + merge entirely);
    // (2) KhG/VhG shared history written bit-identically by all 8 blocks via
    //     PLAIN cached stores -> every block reads only lines it wrote itself,
    //     so no cross-block visibility is ever required;
    // (3) ctx stays in LDS and feeds stage-1 A-frags directly.
    // Barriers/timestep: 5 -> 4. Also reverts R17's scattered 2B y-stores to
    // the coalesced ypbuf+dwordx2 path (R17 cost ~60us).
    fused_kernel<<<dim3(128), dim3(256), 0, stream>>>(p);
}

// Round 8
// 3529.044 us; speedup vs baseline: 2.0868x; 2.0868x over previous
//
#include <hip/hip_runtime.h>
#include <math.h>

#define B_ 256
#define T_ 128
#define D_ 64
#define H_ 512
#define A_ 128
#define O_ 32

typedef __attribute__((ext_vector_type(8))) short short8;
typedef __attribute__((ext_vector_type(8))) unsigned short ushort8;
typedef __attribute__((ext_vector_type(4))) float floatx4;
typedef __attribute__((ext_vector_type(4))) unsigned int uintx4;
typedef unsigned long long ull;

__device__ __forceinline__ float sp_(float x) {
    return fmaxf(x, 0.f) + log1pf(expf(-fabsf(x)));
}
__device__ __forceinline__ float sigm_(float x) {
    return 1.f / (1.f + expf(-x));
}
__device__ __forceinline__ unsigned short f2bf_(float f) {
    unsigned int u = __float_as_uint(f);
    return (unsigned short)((u + 0x7FFFu + ((u >> 16) & 1u)) >> 16);
}
__device__ __forceinline__ float bf2f_(unsigned short u) {
    return __uint_as_float(((unsigned)u) << 16);
}

// ---- raw MALL-coherent (sc0 sc1) ops. R13-R16: no usable sc0-only/XCD scope
// on gfx950; cross-block floor = MALL RT. R19: sentinel-carried data — the
// consumer polls data+sentinel TOGETHER, so a fresh sentinel means the data is
// already in registers (saves the flag-store + post-discovery-load RTs).
__device__ __forceinline__ void ld16sc(uintx4& d, const void* p) {
    asm volatile("global_load_dwordx4 %0, %1, off sc0 sc1"
                 : "=v"(d) : "v"(p) : "memory");
}
__device__ __forceinline__ void ld4sc(float& d, const void* p) {
    asm volatile("global_load_dword %0, %1, off sc0 sc1"
                 : "=v"(d) : "v"(p) : "memory");
}
__device__ __forceinline__ void ld4su(unsigned& d, const void* p) {
    asm volatile("global_load_dword %0, %1, off sc0 sc1"
                 : "=v"(d) : "v"(p) : "memory");
}
__device__ __forceinline__ void st64sc(ull* p, ull v) {
    asm volatile("global_store_dwordx2 %0, %1, off sc0 sc1"
                 :: "v"(p), "v"(v) : "memory");
}
__device__ __forceinline__ void stu32sc(unsigned* p, unsigned v) {
    asm volatile("global_store_dword %0, %1, off sc0 sc1"
                 :: "v"(p), "v"(v) : "memory");
}
__device__ __forceinline__ void vmwait4(uintx4& a, uintx4& b, uintx4& c,
                                        uintx4& d) {
    asm volatile("s_waitcnt vmcnt(0)"
                 : "+v"(a), "+v"(b), "+v"(c), "+v"(d)::"memory");
}
__device__ __forceinline__ void vmwait8(uintx4& a, uintx4& b, uintx4& c,
                                        uintx4& d, uintx4& e, uintx4& f,
                                        uintx4& g, uintx4& h) {
    asm volatile("s_waitcnt vmcnt(0)"
                 : "+v"(a), "+v"(b), "+v"(c), "+v"(d), "+v"(e), "+v"(f),
                   "+v"(g), "+v"(h)::"memory");
}
__device__ __forceinline__ void vmwait16f(float& a0, float& a1, float& a2,
                                          float& a3, float& a4, float& a5,
                                          float& a6, float& a7, float& b0,
                                          float& b1, float& b2, float& b3,
                                          float& b4, float& b5, float& b6,
                                          float& b7) {
    asm volatile("s_waitcnt vmcnt(0)"
                 : "+v"(a0), "+v"(a1), "+v"(a2), "+v"(a3), "+v"(a4), "+v"(a5),
                   "+v"(a6), "+v"(a7), "+v"(b0), "+v"(b1), "+v"(b2), "+v"(b3),
                   "+v"(b4), "+v"(b5), "+v"(b6), "+v"(b7)::"memory");
}
__device__ __forceinline__ void vmwait8u(unsigned& a, unsigned& b, unsigned& c,
                                         unsigned& d, unsigned& e, unsigned& f,
                                         unsigned& g, unsigned& h) {
    asm volatile("s_waitcnt vmcnt(0)"
                 : "+v"(a), "+v"(b), "+v"(c), "+v"(d), "+v"(e), "+v"(f),
                   "+v"(g), "+v"(h)::"memory");
}
__device__ __forceinline__ void vmwait4u(unsigned& a, unsigned& b, unsigned& c,
                                         unsigned& d) {
    asm volatile("s_waitcnt vmcnt(0)"
                 : "+v"(a), "+v"(b), "+v"(c), "+v"(d)::"memory");
}
__device__ __forceinline__ void vmwait1u(unsigned& a) {
    asm volatile("s_waitcnt vmcnt(0)" : "+v"(a)::"memory");
}
__device__ __forceinline__ floatx4 u2f_(uintx4 u) {
    union { uintx4 u; floatx4 f; } c;
    c.u = u;
    return c.f;
}
__device__ __forceinline__ void stf_(float* p, float v) {
    __hip_atomic_store(p, v, __ATOMIC_RELAXED, __HIP_MEMORY_SCOPE_SYSTEM);
}

// ---------------- init: hpack = 0, flags+sentinels = 0 ----------------------
__global__ void init_kernel(unsigned short* __restrict__ hpack,
                            unsigned* __restrict__ bar) {
    int i = blockIdx.x * 256 + threadIdx.x;
    if (i < B_ * H_) hpack[i] = 0;
    if (i < 18432) bar[i] = 0u;  // 8192 flags + 10240 sentinels
}

// -------- pack all weights into MFMA B-frag bf16 order ----------------------
__global__ void pack_w_kernel(const float* __restrict__ W_gd,
                              const float* __restrict__ W_tau,
                              const float* __restrict__ Wk,
                              const float* __restrict__ Wv,
                              unsigned short* __restrict__ Wpack) {
    int gid = blockIdx.x * 256 + threadIdx.x;
    if (gid >= 1114112) return;
    int j = gid & 7;
    int l = (gid >> 3) & 63;
    int kpart = (l >> 4) * 8 + j;
    int npart = l & 15;
    float v;
    if (gid < 786432) {
        int f = gid >> 9;
        int s = f % 3;
        int rem = f / 3;
        int kb = rem & 15, ct = rem >> 4;
        int k = kb * 32 + kpart;
        int c = ct * 16 + npart;
        if (s == 0)      v = W_gd[(size_t)(D_ + k) * 1024 + c];
        else if (s == 1) v = W_gd[(size_t)(D_ + k) * 1024 + 512 + c];
        else             v = W_tau[(size_t)k * 512 + c];
    } else if (gid < 851968) {
        int r = gid - 786432;
        int f = r >> 9;
        int s = f & 1, kb = (f >> 1) & 1, ct = f >> 2;
        int k = kb * 32 + kpart;
        int c = ct * 16 + npart;
        v = W_gd[(size_t)k * 1024 + s * 512 + c];
    } else if (gid < 983040) {
        int r = gid - 851968;
        int f = r >> 9;
        int s = f & 1, kb = (f >> 1) & 3, ct = f >> 3;
        int k = kb * 32 + kpart;
        int c = ct * 16 + npart;
        v = W_gd[(size_t)(D_ + H_ + k) * 1024 + s * 512 + c];
    } else {
        int r = gid - 983040;
        int f = r >> 9;
        int kb = f & 15, c4 = f >> 4;
        int k = kb * 32 + kpart;
        int n = (c4 & 7) * 16 + npart;
        v = (c4 < 8) ? Wk[(size_t)k * A_ + n] : Wv[(size_t)k * A_ + n];
    }
    Wpack[gid] = f2bf_(v);
}

// ---- classic group barrier (final fc only) ----
__device__ __forceinline__ void gsyncF(unsigned* flags, int j, unsigned cnt) {
    asm volatile("s_waitcnt vmcnt(0)" ::: "memory");
    __syncthreads();
    if (threadIdx.x == 0) stu32sc(flags + j * 64, cnt);
    if (threadIdx.x < 8) {
        unsigned v;
        do {
            ld4su(v, flags + threadIdx.x * 64);
            vmwait1u(v);
            if (v >= cnt) break;
            __builtin_amdgcn_s_sleep(1);
        } while (true);
    }
    __syncthreads();
}

struct P {
    const float *x, *dts, *Wq, *bq, *bk, *bv, *b_gd, *b_tau, *gleak, *cm,
        *W_fc, *b_fc;
    float *h, *ctx, *out, *Kpart, *Vpart;
    unsigned short* Kh;  // block-private K history rows (plain ld/st)
    const unsigned short *Wy, *Wx, *Wc, *Wkv;
    unsigned short *hpack, *yapack, *ybpack, *ycpack;
    unsigned* bar;  // [0..8191] flags, [8192..] sentinels [kind][g][src]*16
};

__global__ __launch_bounds__(256, 1) void fused_kernel(P p) {
    const int tid = threadIdx.x;
    const int bid = blockIdx.x;
    const int lane = tid & 63;
    const int wave = tid >> 6;            // 0..3
    const int g = bid & 15;               // group of 8 blocks
    const int j = bid >> 4;               // block within group 0..7
    const int ct = j * 4 + wave;          // channel strip 0..31
    unsigned* flags = p.bar + g * 512;
    unsigned* senbase = p.bar + 8192;
    // sentinel slot for (kind, src): kinds CTX=0, A=1, B=2, C=3, D=4
    #define SEN(kind, src) (senbase + (((kind)*16 + g) * 8 + (src)) * 16)

    __shared__ float WqL[D_ * 129];
    __shared__ float xs4[2][D_];
    __shared__ float q4[2][A_];
    __shared__ float sc4[2][T_];
    __shared__ float red[2][2];
    __shared__ __align__(16) unsigned short AsL[32 * 256];  // 16 KB staged A
    __shared__ __align__(16) unsigned short ypbuf[4 * 256]; // 2 KB transpose
    __shared__ __align__(16) unsigned short As2[2 * 512];   // kv h A-frags
    __shared__ unsigned short VhL[2][A_][136];              // ~70 KB V history

    const int quad = lane >> 4;
    const int c = ct * 16 + (lane & 15);
    const float btau = p.b_tau[c];
    const float lk = sp_(p.cm[c]) + sp_(p.gleak[c]) + 1e-6f;
    const float bgd_g = p.b_gd[c];
    const float bgd_d = p.b_gd[512 + c];
    const int aoff = (quad >> 1) * 256 + (lane & 15) * 16 + (quad & 1) * 8;
    const int ypw = wave * 256 + (lane & 15);

    const int sub = tid >> 7;             // 0..1
    const int tl = tid & 127;
    const int r = g * 16 + j * 2 + sub;   // this block's 2 attention rows
    const int rrow = r & 15;

    // ---- persistent register weights: 60 frags (240 VGPRs) ----
    short8 wg[16], wd[16], wt[16];
    short8 wxg[2], wxd[2], wcg[4], wcd[4];
    {
        const short8* Wy8 = (const short8*)p.Wy;
        #pragma unroll
        for (int kb = 0; kb < 16; ++kb) {
            wg[kb] = Wy8[((ct * 16 + kb) * 3 + 0) * 64 + lane];
            wd[kb] = Wy8[((ct * 16 + kb) * 3 + 1) * 64 + lane];
            wt[kb] = Wy8[((ct * 16 + kb) * 3 + 2) * 64 + lane];
        }
        const short8* Wx8 = (const short8*)p.Wx;
        const short8* Wc8 = (const short8*)p.Wc;
        #pragma unroll
        for (int kb = 0; kb < 2; ++kb) {
            wxg[kb] = Wx8[((ct * 2 + kb) * 2 + 0) * 64 + lane];
            wxd[kb] = Wx8[((ct * 2 + kb) * 2 + 1) * 64 + lane];
        }
        #pragma unroll
        for (int kb = 0; kb < 4; ++kb) {
            wcg[kb] = Wc8[((ct * 4 + kb) * 2 + 0) * 64 + lane];
            wcd[kb] = Wc8[((ct * 4 + kb) * 2 + 1) * 64 + lane];
        }
    }

    for (int i = tid; i < D_ * A_; i += 256) {
        int d = i >> 7, a = i & 127;
        WqL[d * 129 + a] = p.Wq[i];
    }

    floatx4 hreg = {0.f, 0.f, 0.f, 0.f};
    floatx4 rk1, rk2, rk3, baseg, based, ycur, dt4;

    const short8* Wkv8 = (const short8*)p.Wkv;

    __syncthreads();  // WqL ready

    for (int t = 0; t < T_; ++t) {
        // ---------- phase A: poll stage4(t-1) data + attention --------------
        {
            // fused poll: K/V partials + hpack chunks + 8 D-sentinels.
            // stage4 of t-1 stored sen_D = t; at t=0 expv=0 passes trivially
            // (hpack zero-initialized; kk/vv unused at t=0).
            float kk[8], vv[8];
            uintx4 av[4];
            {
                const unsigned short* src = p.hpack + g * 8192;
                const unsigned expv = (unsigned)t;
                unsigned s0, s1, s2, s3, s4, s5, s6, s7;
                for (;;) {
                    #pragma unroll
                    for (int jj = 0; jj < 8; ++jj) {
                        ld4sc(kk[jj],
                              p.Kpart + ((g * 8 + jj) * 16 + rrow) * 128 + tl);
                        ld4sc(vv[jj],
                              p.Vpart + ((g * 8 + jj) * 16 + rrow) * 128 + tl);
                    }
                    #pragma unroll
                    for (int i = 0; i < 4; ++i)
                        ld16sc(av[i], src + (size_t)tid * 8 + i * 2048);
                    ld4su(s0, SEN(4, 0)); ld4su(s1, SEN(4, 1));
                    ld4su(s2, SEN(4, 2)); ld4su(s3, SEN(4, 3));
                    ld4su(s4, SEN(4, 4)); ld4su(s5, SEN(4, 5));
                    ld4su(s6, SEN(4, 6)); ld4su(s7, SEN(4, 7));
                    vmwait16f(kk[0], kk[1], kk[2], kk[3], kk[4], kk[5], kk[6],
                              kk[7], vv[0], vv[1], vv[2], vv[3], vv[4], vv[5],
                              vv[6], vv[7]);
                    vmwait4(av[0], av[1], av[2], av[3]);
                    vmwait8u(s0, s1, s2, s3, s4, s5, s6, s7);
                    if (s0 >= expv && s1 >= expv && s2 >= expv && s3 >= expv &&
                        s4 >= expv && s5 >= expv && s6 >= expv && s7 >= expv)
                        break;
                    __builtin_amdgcn_s_sleep(1);
                }
            }
            #pragma unroll
            for (int i = 0; i < 4; ++i)
                ((uintx4*)AsL)[tid + i * 256] = av[i];
            if (t > 0) {
                float ks = p.bk[tl], vs = p.bv[tl];
                #pragma unroll
                for (int jj = 0; jj < 8; ++jj) {
                    ks += kk[jj];
                    vs += vv[jj];
                }
                p.Kh[(size_t)(r * T_ + (t - 1)) * A_ + tl] = f2bf_(ks);
                VhL[sub][tl][t - 1] = f2bf_(vs);
            }
            if (tl < 16)
                ((float4*)xs4[sub])[tl] =
                    ((const float4*)&p.x[(r * T_ + t) * D_])[tl];
            __syncthreads();  // AsL + xs4 ready
            float qa = p.bq[tl];
            #pragma unroll 8
            for (int d = 0; d < D_; ++d) qa += xs4[sub][d] * WqL[d * 129 + tl];
            q4[sub][tl] = qa;
            __syncthreads();
            if (t == 0) {
                stf_(p.ctx + r * A_ + tl, 0.f);
            } else {
                const float rscale = 0.08838834764831845f;  // 1/sqrt(128)
                const int grp = tl >> 4, ln = tl & 15;
                float qv[8];
                #pragma unroll
                for (int i = 0; i < 8; ++i) qv[i] = q4[sub][ln * 8 + i];
                for (int s = grp; s < t; s += 8) {
                    ushort8 k8 = *((const ushort8*)(p.Kh +
                                     (size_t)(r * T_ + s) * A_) + ln);
                    float a2 = 0.f;
                    #pragma unroll
                    for (int i = 0; i < 8; ++i) a2 += bf2f_(k8[i]) * qv[i];
                    #pragma unroll
                    for (int off = 8; off > 0; off >>= 1)
                        a2 += __shfl_xor(a2, off, 16);
                    if (ln == 0) sc4[sub][s] = a2 * rscale;
                }
                __syncthreads();
                float mloc = -1e30f;
                for (int s = tl; s < t; s += 128) mloc = fmaxf(mloc, sc4[sub][s]);
                #pragma unroll
                for (int off = 32; off > 0; off >>= 1)
                    mloc = fmaxf(mloc, __shfl_xor(mloc, off, 64));
                if (lane == 0) red[sub][wave & 1] = mloc;
                __syncthreads();
                float m = fmaxf(red[sub][0], red[sub][1]);
                float ssum = 0.f;
                for (int s = tl; s < t; s += 128) {
                    float e = expf(sc4[sub][s] - m);
                    sc4[sub][s] = e;
                    ssum += e;
                }
                #pragma unroll
                for (int off = 32; off > 0; off >>= 1)
                    ssum += __shfl_xor(ssum, off, 64);
                __syncthreads();
                if (lane == 0) red[sub][wave & 1] = ssum;
                __syncthreads();
                float rs = 1.f / (red[sub][0] + red[sub][1]);
                const unsigned short* Vrow = &VhL[sub][tl][0];
                float ca0 = 0.f, ca1 = 0.f;
                int s0 = 0;
                for (; s0 + 16 <= t; s0 += 16) {
                    ushort8 v0 = *(const ushort8*)(Vrow + s0);
                    ushort8 v1 = *(const ushort8*)(Vrow + s0 + 8);
                    #pragma unroll
                    for (int i = 0; i < 8; ++i) {
                        ca0 += sc4[sub][s0 + i] * bf2f_(v0[i]);
                        ca1 += sc4[sub][s0 + 8 + i] * bf2f_(v1[i]);
                    }
                }
                if (s0 + 8 <= t) {
                    ushort8 v0 = *(const ushort8*)(Vrow + s0);
                    #pragma unroll
                    for (int i = 0; i < 8; ++i)
                        ca0 += sc4[sub][s0 + i] * bf2f_(v0[i]);
                    s0 += 8;
                }
                for (; s0 < t; ++s0) ca0 += sc4[sub][s0] * bf2f_(Vrow[s0]);
                stf_(p.ctx + r * A_ + tl, (ca0 + ca1) * rs);
            }
        }
        // phase A done: drain ctx, publish ctx sentinel (value t+1)
        asm volatile("s_waitcnt vmcnt(0)" ::: "memory");
        __syncthreads();
        if (tid == 0) stu32sc(SEN(0, j), (unsigned)(t + 1));

        // ---------- stage 1 (poll ctx per-thread; AsL already staged) -------
        {
            const int mrow = lane & 15;
            const float* crow = &p.ctx[(g * 16 + mrow) * A_];
            uintx4 cc[8];
            {
                const unsigned* senp = SEN(0, mrow >> 1);
                const unsigned expv = (unsigned)(t + 1);
                unsigned sv;
                for (;;) {
                    #pragma unroll
                    for (int kb = 0; kb < 4; ++kb) {
                        ld16sc(cc[2 * kb], crow + kb * 32 + quad * 8);
                        ld16sc(cc[2 * kb + 1], crow + kb * 32 + quad * 8 + 4);
                    }
                    ld4su(sv, senp);
                    vmwait8(cc[0], cc[1], cc[2], cc[3], cc[4], cc[5], cc[6],
                            cc[7]);
                    vmwait1u(sv);
                    if (sv >= expv) break;
                    __builtin_amdgcn_s_sleep(1);
                }
            }
            #pragma unroll
            for (int i = 0; i < 4; ++i)
                dt4[i] = p.dts[(g * 16 + quad * 4 + i) * T_ + t];

            floatx4 bg = {0.f, 0.f, 0.f, 0.f};
            floatx4 bd = {0.f, 0.f, 0.f, 0.f};
            const float4* xrow =
                (const float4*)&p.x[((g * 16 + mrow) * T_ + t) * D_];
            #pragma unroll
            for (int kb = 0; kb < 2; ++kb) {
                float4 u = xrow[kb * 8 + quad * 2], v = xrow[kb * 8 + quad * 2 + 1];
                short8 ax;
                ax[0] = (short)f2bf_(u.x); ax[1] = (short)f2bf_(u.y);
                ax[2] = (short)f2bf_(u.z); ax[3] = (short)f2bf_(u.w);
                ax[4] = (short)f2bf_(v.x); ax[5] = (short)f2bf_(v.y);
                ax[6] = (short)f2bf_(v.z); ax[7] = (short)f2bf_(v.w);
                bg = __builtin_amdgcn_mfma_f32_16x16x32_bf16(ax, wxg[kb], bg, 0, 0, 0);
                bd = __builtin_amdgcn_mfma_f32_16x16x32_bf16(ax, wxd[kb], bd, 0, 0, 0);
            }
            #pragma unroll
            for (int kb = 0; kb < 4; ++kb) {
                floatx4 f0 = u2f_(cc[2 * kb]), f1 = u2f_(cc[2 * kb + 1]);
                short8 ac;
                ac[0] = (short)f2bf_(f0[0]); ac[1] = (short)f2bf_(f0[1]);
                ac[2] = (short)f2bf_(f0[2]); ac[3] = (short)f2bf_(f0[3]);
                ac[4] = (short)f2bf_(f1[0]); ac[5] = (short)f2bf_(f1[1]);
                ac[6] = (short)f2bf_(f1[2]); ac[7] = (short)f2bf_(f1[3]);
                bg = __builtin_amdgcn_mfma_f32_16x16x32_bf16(ac, wcg[kb], bg, 0, 0, 0);
                bd = __builtin_amdgcn_mfma_f32_16x16x32_bf16(ac, wcd[kb], bd, 0, 0, 0);
            }
            floatx4 ag = {0.f, 0.f, 0.f, 0.f};
            floatx4 ad = {0.f, 0.f, 0.f, 0.f};
            floatx4 at = {0.f, 0.f, 0.f, 0.f};
            #pragma unroll
            for (int kb = 0; kb < 16; ++kb) {
                short8 a = *(const short8*)(AsL + kb * 512 + aoff);
                ag = __builtin_amdgcn_mfma_f32_16x16x32_bf16(a, wg[kb], ag, 0, 0, 0);
                ad = __builtin_amdgcn_mfma_f32_16x16x32_bf16(a, wd[kb], ad, 0, 0, 0);
                at = __builtin_amdgcn_mfma_f32_16x16x32_bf16(a, wt[kb], at, 0, 0, 0);
            }
            #pragma unroll
            for (int i = 0; i < 4; ++i) {
                baseg[i] = bg[i] + bgd_g;
                based[i] = bd[i] + bgd_d;
                float gate = ag[i] + baseg[i];
                float dyn = ad[i] + based[i];
                float tau = sp_(at[i] + btau);
                float ki = (sigm_(gate) * tanhf(dyn) - hreg[i]) / (tau + lk);
                rk1[i] = ki;
                float yn = hreg[i] + dt4[i] * ki * (1.f / 3.f);
                ycur[i] = yn;
                ypbuf[ypw + (quad * 4 + i) * 16] = f2bf_(yn);
            }
            __syncthreads();
            st64sc((ull*)p.yapack + g * 2048 + j * 256 + tid,
                   ((const ull*)ypbuf)[tid]);
        }
        asm volatile("s_waitcnt vmcnt(0)" ::: "memory");
        __syncthreads();
        if (tid == 0) stu32sc(SEN(1, j), (unsigned)(t + 1));

        // ---------- stages 2..4 (A -> B -> C -> hpack) ----------
        #pragma unroll 1
        for (int stage = 2; stage <= 4; ++stage) {
            const unsigned short* ysrc =
                (stage == 2) ? p.yapack : (stage == 3) ? p.ybpack : p.ycpack;
            unsigned short* ydst =
                (stage == 2) ? p.ybpack : (stage == 3) ? p.ycpack : p.hpack;
            const int senk = stage - 1;  // src sentinel kind
            {
                const unsigned short* src = ysrc + g * 8192;
                const unsigned expv = (unsigned)(t + 1);
                const int sb = tid >> 7;
                uintx4 av[4];
                unsigned s0, s1, s2, s3;
                for (;;) {
                    #pragma unroll
                    for (int i = 0; i < 4; ++i)
                        ld16sc(av[i], src + (size_t)tid * 8 + i * 2048);
                    ld4su(s0, SEN(senk, sb + 0));
                    ld4su(s1, SEN(senk, sb + 2));
                    ld4su(s2, SEN(senk, sb + 4));
                    ld4su(s3, SEN(senk, sb + 6));
                    vmwait4(av[0], av[1], av[2], av[3]);
                    vmwait4u(s0, s1, s2, s3);
                    if (s0 >= expv && s1 >= expv && s2 >= expv && s3 >= expv)
                        break;
                    __builtin_amdgcn_s_sleep(1);
                }
                #pragma unroll
                for (int i = 0; i < 4; ++i)
                    ((uintx4*)AsL)[tid + i * 256] = av[i];
            }
            __syncthreads();
            floatx4 ag = {0.f, 0.f, 0.f, 0.f};
            floatx4 ad = {0.f, 0.f, 0.f, 0.f};
            floatx4 at = {0.f, 0.f, 0.f, 0.f};
            #pragma unroll
            for (int kb = 0; kb < 16; ++kb) {
                short8 a = *(const short8*)(AsL + kb * 512 + aoff);
                ag = __builtin_amdgcn_mfma_f32_16x16x32_bf16(a, wg[kb], ag, 0, 0, 0);
                ad = __builtin_amdgcn_mfma_f32_16x16x32_bf16(a, wd[kb], ad, 0, 0, 0);
                at = __builtin_amdgcn_mfma_f32_16x16x32_bf16(a, wt[kb], at, 0, 0, 0);
            }
            const int lane_p = ((c >> 3) & 3) * 16;
            #pragma unroll
            for (int i = 0; i < 4; ++i) {
                float gate = ag[i] + baseg[i];
                float dyn = ad[i] + based[i];
                float tau = sp_(at[i] + btau);
                float ki = (sigm_(gate) * tanhf(dyn) - ycur[i]) / (tau + lk);
                float yn;
                if (stage == 2) {
                    rk2[i] = ki;
                    yn = hreg[i] + dt4[i] * (ki - rk1[i] * (1.f / 3.f));
                } else if (stage == 3) {
                    rk3[i] = ki;
                    yn = hreg[i] + dt4[i] * (rk1[i] - rk2[i] + ki);
                } else {
                    yn = hreg[i] +
                         dt4[i] * (rk1[i] + 3.f * rk2[i] + 3.f * rk3[i] + ki) * 0.125f;
                    hreg[i] = yn;
                }
                ycur[i] = yn;
                ypbuf[ypw + (quad * 4 + i) * 16] = f2bf_(yn);
                if (stage == 4)
                    As2[(wave >> 1) * 512 + (c & 7) +
                        (lane_p + quad * 4 + i) * 8] = f2bf_(yn);
            }
            __syncthreads();
            st64sc((ull*)ydst + g * 2048 + j * 256 + tid,
                   ((const ull*)ypbuf)[tid]);
            if (stage == 4) {
                #pragma unroll
                for (int h4 = 0; h4 < 4; ++h4) {
                    const int c4 = wave + h4 * 4;  // 0..15 (0..7=K, 8..15=V)
                    floatx4 acc = {0.f, 0.f, 0.f, 0.f};
                    #pragma unroll
                    for (int kk2 = 0; kk2 < 2; ++kk2) {
                        short8 a = *(const short8*)(As2 + (kk2 * 64 + lane) * 8);
                        acc = __builtin_amdgcn_mfma_f32_16x16x32_bf16(
                            a, Wkv8[(c4 * 16 + (j * 2 + kk2)) * 64 + lane], acc,
                            0, 0, 0);
                    }
                    const int ac = (c4 & 7) * 16 + (lane & 15);
                    float* part = (c4 < 8) ? p.Kpart : p.Vpart;
                    #pragma unroll
                    for (int i = 0; i < 4; ++i)
                        stf_(part + ((g * 8 + j) * 16 + quad * 4 + i) * 128 + ac,
                             acc[i]);
                }
            }
            asm volatile("s_waitcnt vmcnt(0)" ::: "memory");
            __syncthreads();
            if (tid == 0) stu32sc(SEN(stage, j), (unsigned)(t + 1));
        }
    }

    // ---------- write final h, then fc ----------
    #pragma unroll
    for (int i = 0; i < 4; ++i)
        stf_(p.h + (g * 16 + quad * 4 + i) * H_ + c, hreg[i]);
    gsyncF(flags, j, 1u);
    {
        const int o = tl & 31, ks = tl >> 5;  // ks 0..3
        float acc = 0.f;
        const float* hrow = p.h + r * H_ + ks * 128;
        const float* wcol = p.W_fc + ks * 128 * O_ + o;
        #pragma unroll 1
        for (int rd = 0; rd < 4; ++rd) {
            uintx4 hh[8];
            #pragma unroll
            for (int i = 0; i < 8; ++i)
                ld16sc(hh[i], hrow + rd * 32 + i * 4);
            vmwait8(hh[0], hh[1], hh[2], hh[3], hh[4], hh[5], hh[6], hh[7]);
            #pragma unroll
            for (int i = 0; i < 8; ++i) {
                floatx4 f = u2f_(hh[i]);
                #pragma unroll
                for (int e = 0; e < 4; ++e)
                    acc += f[e] * wcol[(rd * 32 + i * 4 + e) * O_];
            }
        }
        sc4[sub][tl] = acc;
        __syncthreads();
        if (ks == 0)
            p.out[r * O_ + o] = acc + sc4[sub][o + 32] + sc4[sub][o + 64] +
                                sc4[sub][o + 96] + p.b_fc[o];
    }
    #undef SEN
}

extern "C" void kernel_launch(void* const* d_in, const int* in_sizes, int n_in,
                              void* d_out, int out_size, void* d_ws,
                              size_t ws_size, hipStream_t stream) {
    (void)in_sizes; (void)n_in; (void)out_size; (void)ws_size;
    P p;
    p.x = (const float*)d_in[0];
    p.dts = (const float*)d_in[1];
    p.Wq = (const float*)d_in[2];
    p.bq = (const float*)d_in[3];
    const float* Wk = (const float*)d_in[4];
    p.bk = (const float*)d_in[5];
    const float* Wv = (const float*)d_in[6];
    p.bv = (const float*)d_in[7];
    const float* W_gd = (const float*)d_in[8];
    p.b_gd = (const float*)d_in[9];
    const float* W_tau = (const float*)d_in[10];
    p.b_tau = (const float*)d_in[11];
    p.gleak = (const float*)d_in[12];
    p.cm = (const float*)d_in[13];
    p.W_fc = (const float*)d_in[14];
    p.b_fc = (const float*)d_in[15];
    p.out = (float*)d_out;

    float* ws = (float*)d_ws;
    p.h = ws;                            // B*H fp32
    p.ctx = p.h + B_ * H_;               // B*A fp32
    p.Kpart = p.ctx + B_ * A_;           // 128*16*128 fp32
    p.Vpart = p.Kpart + 262144;
    unsigned short* Wpack = (unsigned short*)(p.Vpart + 262144);
    p.Wy = Wpack;                        // 786432 ushorts
    p.Wx = Wpack + 786432;               // 65536
    p.Wc = Wpack + 851968;               // 131072
    p.Wkv = Wpack + 983040;              // 131072
    p.hpack = Wpack + 1114112;           // B*H ushorts (buffer D)
    p.yapack = p.hpack + B_ * H_;        // buffer A
    p.ybpack = p.yapack + B_ * H_;       // buffer B
    p.ycpack = p.ybpack + B_ * H_;       // buffer C (new, kills WAR hazards)
    p.Kh = p.ycpack + B_ * H_;           // B*T*A bf16 (block-private rows)
    p.bar = (unsigned*)(p.Kh + (size_t)B_ * T_ * A_);  // flags + sentinels

    init_kernel<<<512, 256, 0, stream>>>(p.hpack, p.bar);
    pack_w_kernel<<<4352, 256, 0, stream>>>(W_gd, W_tau, Wk, Wv, Wpack);

    // 128 blocks x 256 threads, launch_bounds(256,1).
    // R18 post-mortem: redundant-attention fusion regressed 2x (184M LDS bank
    // conflicts + serial global load-use chains in PV). Reverted to the R16
    // 5-phase compute bodies (best measured: 3536us steady).
    // R19: SENTINEL-CARRIED DATA replaces the barrier+flag protocol. Each
    // producer drains its data stores (vmcnt0 + syncthreads) then stores a
    // monotone per-(phase,src) sentinel. Consumers poll DATA+SENTINEL in one
    // batched sc0 sc1 load round: a fresh sentinel implies the just-loaded
    // data is valid (sentinel stored after data reached MALL; polls served at
    // MALL). Cuts the per-phase chain from ~4 MALL RTs (drain, flag store,
    // poll discovery, data reload) to ~2-2.5 (drain, poll-hit-with-data).
    // WAR safety: 4 distinct y buffers (A->B->C->hpack); each timestep gates
    // on all-8 stage4 sentinels, bounding inter-block skew to < 1 timestep,
    // and each buffer is written once per timestep. Final fc keeps a classic
    // flag barrier (once).
    fused_kernel<<<dim3(128), dim3(256), 0, stream>>>(p);
}